// Round 7
// baseline (108.876 us; speedup 1.0000x reference)
//
#include <hip/hip_runtime.h>
#include <hip/hip_bf16.h>

// ---- problem constants ----
#define BB 8
#define TT 4096
#define DD 512
#define MM (BB*TT)          // 32768 rows
#define DECAYF 0.95f
#define OMDECAYF (1.0f - 0.95f)

typedef __attribute__((ext_vector_type(8))) short bf16x8;
typedef __attribute__((ext_vector_type(4))) float f32x4;

__device__ __forceinline__ float gelu_f(float x){
  return 0.5f * x * (1.0f + erff(x * 0.70710678118654752f));
}

__device__ __forceinline__ unsigned short f2bf(float x){
  unsigned u = __float_as_uint(x);
  unsigned r = (u + 0x7FFFu + ((u >> 16) & 1u)) >> 16;
  return (unsigned short)r;
}

// ============ K1: blocks 0-7 = per-batch {spk_ctx, s_vec, coarse, scan,
//              baseline out, segmented compaction}; blocks 8-71 = transpose ====
__global__ __launch_bounds__(512) void fused_pre_kernel(
    const float* __restrict__ spk_embed, const float* __restrict__ spk_W,
    const float* __restrict__ spk_b, const float* __restrict__ rW1,
    const float* __restrict__ cW1, const float* __restrict__ cb1,
    const float* __restrict__ cW2, const float* __restrict__ cb2,
    const float* __restrict__ grate, const float* __restrict__ la_g,
    const int* __restrict__ um, const int* __restrict__ sm,
    const int* __restrict__ zm, const float* __restrict__ stab_g,
    const float* __restrict__ lre,
    unsigned short* __restrict__ wqt, float* __restrict__ s_vec,
    float* __restrict__ rate_seq, float* __restrict__ gterm_a,
    float* __restrict__ rgate_a, int* __restrict__ active_list,
    int* __restrict__ acount, float* __restrict__ out)
{
  int blk = blockIdx.x, t = threadIdx.x;
  if (blk >= 8){
    // ---- transpose Wq (k-major f32) -> WqT (n-major bf16) ----
    __shared__ float tile[64][65];
    int tb = blk - 8;
    int nb = (tb & 7) * 64, kb = (tb >> 3) * 64;
    int tx = t & 63, ty = t >> 6;
    #pragma unroll
    for (int i = 0; i < 8; ++i){
      int k = ty + i*8;
      tile[k][tx] = rW1[(long)(kb + k)*DD + nb + tx];
    }
    __syncthreads();
    #pragma unroll
    for (int i = 0; i < 8; ++i){
      int nl = ty + i*8;
      wqt[(long)(nb + nl)*DD + kb + tx] = f2bf(tile[tx][nl]);
    }
    return;
  }

  // ================= per-batch chain, one block per batch =================
  __shared__ float se[DD];
  __shared__ float sc[DD];
  __shared__ float wred[8];
  __shared__ float cs_sh;
  __shared__ float wAg[8], wBg[8], wSg[8];
  __shared__ int wcnt[8];
  int b = blk;
  int lane = t & 63, wid = t >> 6;

  // ---- phase A: spk_ctx = tanh(spk_embed @ spk_W + spk_b) (kept in LDS) ----
  se[t] = spk_embed[b*DD + t];
  __syncthreads();
  {
    float a = spk_b[t];
    #pragma unroll 8
    for (int k = 0; k < DD; ++k) a = fmaf(se[k], spk_W[(long)k*DD + t], a);
    sc[t] = tanhf(a);
  }
  __syncthreads();

  // ---- phase B: s_vec = sc@Ws ; coarse scalar ----
  {
    float grcv = grate[b];
    float a1 = 0.f;
    float a2 = cb1[t] + grcv * cW1[(long)DD*DD + t];   // row 512 = grc coeff
    #pragma unroll 4
    for (int k = 0; k < DD; ++k){
      float s = sc[k];
      a1 = fmaf(s, rW1[(long)(DD + k)*DD + t], a1);    // Ws = res_W1[D:2D]
      a2 = fmaf(s, cW1[(long)k*DD + t], a2);
    }
    s_vec[b*DD + t] = a1;
    float hv = gelu_f(a2) * cW2[t];
    #pragma unroll
    for (int sh = 1; sh < 64; sh <<= 1) hv += __shfl_xor(hv, sh, 64);
    if (lane == 0) wred[wid] = hv;
  }
  __syncthreads();
  if (t == 0){
    float s = cb2[0];
    #pragma unroll
    for (int w = 0; w < 8; ++w) s += wred[w];
    cs_sh = 0.2f * tanhf(s);
  }
  __syncthreads();
  float cs = cs_sh;

  // ---- phase C: scan + gterm/rgate + baseline out + segmented compaction ----
  int base = b*TT + t*8;
  float4 la0 = *(const float4*)(la_g + base);
  float4 la1 = *(const float4*)(la_g + base + 4);
  int4 u0 = *(const int4*)(um + base), u1 = *(const int4*)(um + base + 4);
  int4 s0 = *(const int4*)(sm + base), s1 = *(const int4*)(sm + base + 4);
  int4 z0 = *(const int4*)(zm + base), z1 = *(const int4*)(zm + base + 4);
  float4 st0 = *(const float4*)(stab_g + base), st1 = *(const float4*)(stab_g + base + 4);
  float lav[8] = {la0.x,la0.y,la0.z,la0.w,la1.x,la1.y,la1.z,la1.w};
  int uv[8] = {u0.x,u0.y,u0.z,u0.w,u1.x,u1.y,u1.z,u1.w};
  int sv[8] = {s0.x,s0.y,s0.z,s0.w,s1.x,s1.y,s1.z,s1.w};
  int zv[8] = {z0.x,z0.y,z0.z,z0.w,z1.x,z1.y,z1.z,z1.w};
  float stv_[8] = {st0.x,st0.y,st0.z,st0.w,st1.x,st1.y,st1.z,st1.w};
  float spv[8], cmv[8], slv[8], stv[8];

  float A = 1.f, Bv = 0.f, S = 0.f;
  #pragma unroll
  for (int i = 0; i < 8; ++i){
    float m = uv[i] > 0 ? 1.f : 0.f;
    float sealed = sv[i] > 0 ? 1.f : 0.f;
    float sil = (zv[i] > 0 ? 1.f : 0.f) * m;
    float commit = m * sealed;
    float speech = commit * (1.f - sil);
    spv[i] = speech; cmv[i] = commit; slv[i] = commit * sil;
    stv[i] = fminf(fmaxf(stv_[i], 0.f), 1.f) * m;
    if (speech > 0.f){
      Bv = DECAYF*Bv + OMDECAYF*lav[i];
      A *= DECAYF;
      S += 1.f;
    }
  }
  #pragma unroll
  for (int d = 1; d < 64; d <<= 1){
    float Au = __shfl_up(A, d, 64);
    float Bu = __shfl_up(Bv, d, 64);
    float Su = __shfl_up(S, d, 64);
    if (lane >= d){ Bv = A*Bu + Bv; A = A*Au; S += Su; }
  }
  if (lane == 63){ wAg[wid] = A; wBg[wid] = Bv; wSg[wid] = S; }
  float Ale = __shfl_up(A, 1, 64), Ble = __shfl_up(Bv, 1, 64), Sle = __shfl_up(S, 1, 64);
  if (lane == 0){ Ale = 1.f; Ble = 0.f; Sle = 0.f; }
  __syncthreads();
  float Awp = 1.f, Bwp = 0.f, Swp = 0.f;
  for (int w = 0; w < wid; ++w){
    Bwp = wAg[w]*Bwp + wBg[w];
    Awp = wAg[w]*Awp;
    Swp += wSg[w];
  }
  float Bex = Ale*Bwp + Ble;
  float Aex = Ale*Awp;
  float Sex = Swp + Sle;

  float rate = Aex*lre[b] + Bex;
  float ps = Sex;
  float grc = grate[b];
  float ro[8], go[8], rg[8], oo[8];
  #pragma unroll
  for (int i = 0; i < 8; ++i){
    ro[i] = rate;
    float g = (grc - rate + cs) * cmv[i];
    float cold = fminf(ps * 0.5f, 1.f);                        // COLD_RUNS=2
    float shortg = fminf(fmaxf(expf(lav[i]) - 1.f, 0.f), 1.f); // MIN_DUR=2
    float rgv = cold * shortg * stv[i] * spv[i];
    go[i] = g; rg[i] = rgv;
    oo[i] = fminf(fmaxf(g, -1.2f), 1.2f) * spv[i]
          + fminf(fmaxf(g, -0.35f), 0.35f) * slv[i];
    if (spv[i] > 0.f){
      rate = DECAYF*rate + OMDECAYF*lav[i];
      ps += 1.f;
    }
  }
  *(float4*)(rate_seq + base)     = make_float4(ro[0],ro[1],ro[2],ro[3]);
  *(float4*)(rate_seq + base + 4) = make_float4(ro[4],ro[5],ro[6],ro[7]);
  *(float4*)(gterm_a + base)      = make_float4(go[0],go[1],go[2],go[3]);
  *(float4*)(gterm_a + base + 4)  = make_float4(go[4],go[5],go[6],go[7]);
  *(float4*)(rgate_a + base)      = make_float4(rg[0],rg[1],rg[2],rg[3]);
  *(float4*)(rgate_a + base + 4)  = make_float4(rg[4],rg[5],rg[6],rg[7]);
  *(float4*)(out + base)          = make_float4(oo[0],oo[1],oo[2],oo[3]);
  *(float4*)(out + base + 4)      = make_float4(oo[4],oo[5],oo[6],oo[7]);

  // --- segmented compaction (no atomics): actives of batch b at b*TT+... ---
  int nact = 0;
  #pragma unroll
  for (int i = 0; i < 8; ++i) nact += (rg[i] != 0.f) ? 1 : 0;
  int inc = nact;
  #pragma unroll
  for (int d = 1; d < 64; d <<= 1){
    int u = __shfl_up(inc, d, 64);
    if (lane >= d) inc += u;
  }
  int myex = inc - nact;
  if (lane == 63) wcnt[wid] = inc;
  __syncthreads();
  int wbase = 0;
  for (int w = 0; w < wid; ++w) wbase += wcnt[w];
  int pos = wbase + myex;
  int* alist = active_list + b*TT;
  #pragma unroll
  for (int i = 0; i < 8; ++i){
    if (rg[i] != 0.f) alist[pos++] = base + i;
  }
  if (t == 0){
    int total = 0;
    #pragma unroll
    for (int w = 0; w < 8; ++w) total += wcnt[w];
    acount[b] = total;
  }
}

// ============== K2: fused Q-build + GEMM + epilogue on ACTIVE rows ===========
// BM=32, BN=512 (full N -> row-dot block-local), BK=32, 8 waves x (32x64)
// per-batch segments: tile p -> (batch, 32-row range) from acount[8]
__global__ __launch_bounds__(512) void gemm_kernel(
    const int* __restrict__ content, const float* __restrict__ la_g,
    const float* __restrict__ sep, const float* __restrict__ edge,
    const float* __restrict__ emb, const float* __restrict__ fW,
    const float* __restrict__ fb, const float* __restrict__ rate_seq,
    const unsigned short* __restrict__ wqt,
    const float* __restrict__ s_vec, const float* __restrict__ rW1,
    const float* __restrict__ rb1, const float* __restrict__ rW2,
    const float* __restrict__ rb2,
    const float* __restrict__ gterm_a, const float* __restrict__ rgate_a,
    const int* __restrict__ active_list, const int* __restrict__ acount,
    float* __restrict__ out)
{
  __shared__ unsigned short Af[16*32*32];    // [kc][row][32k] = 32 KB
  __shared__ unsigned short Bs[2][512*32];   // 64 KB
  __shared__ float part[8][32];              // 1 KB
  __shared__ int seg_sh[3];                  // {batch, lo, cnt}
  int tid = threadIdx.x, wid = tid >> 6, lane = tid & 63;

  if (tid == 0){
    int p = blockIdx.x, cum = 0, sb = -1, slo = 0, scnt = 0;
    #pragma unroll
    for (int b = 0; b < BB; ++b){
      int c = acount[b];
      int nb = (c + 31) >> 5;
      if (sb < 0 && p < cum + nb){ sb = b; slo = (p - cum) * 32; scnt = c; }
      cum += nb;
    }
    seg_sh[0] = sb; seg_sh[1] = slo; seg_sh[2] = scnt;
  }
  __syncthreads();
  int seg_b = seg_sh[0], seg_lo = seg_sh[1], seg_cnt = seg_sh[2];
  if (seg_b < 0) return;
  const int* alist = active_list + seg_b*TT;
  const char* wbase = (const char*)wqt;

  auto stageB = [&](int buf, int kc){
    int k0b = kc * 64;  // byte offset into each 1024B (512-elem bf16) row
    #pragma unroll
    for (int i = 0; i < 4; ++i){
      int j = wid*4 + i;                      // 32 wave-issues for 512 n-rows
      int n = j*16 + (lane >> 2);
      int slot = (lane & 3) ^ ((n >> 1) & 3);
      const char* src = wbase + (long)n*1024 + k0b + slot*16;
      char* dst = (char*)&Bs[buf][0] + j*1024 + (lane << 4);
      __builtin_amdgcn_global_load_lds(
          (const __attribute__((address_space(1))) void*)src,
          (__attribute__((address_space(3))) void*)dst, 16, 0, 0);
    }
  };

  stageB(0, 0);

  // ---- build A tile: thread -> row rr = tid>>4, k-chunk kc = tid&15 ----
  {
    int rr = tid >> 4, kc = tid & 15;
    int p = seg_lo + rr; if (p > seg_cnt-1) p = seg_cnt-1;
    int gr = alist[p];
    float la = la_g[gr], rate = rate_seq[gr];
    float sepv = sep[gr], edgev = edge[gr];
    int k0 = kc * 32;
    const float* er = emb + (long)content[gr]*DD + k0;
    union { bf16x8 v[4]; unsigned short h[32]; } pk;
    #pragma unroll
    for (int i = 0; i < 32; i += 4){
      float4 e  = *(const float4*)(er + i);
      float4 w0 = *(const float4*)(fW + 0*DD + k0 + i);
      float4 w1 = *(const float4*)(fW + 1*DD + k0 + i);
      float4 w3 = *(const float4*)(fW + 3*DD + k0 + i);
      float4 w4 = *(const float4*)(fW + 4*DD + k0 + i);
      float4 bb = *(const float4*)(fb + k0 + i);
      pk.h[i+0] = f2bf(gelu_f(e.x + la*w0.x + rate*w1.x + sepv*w3.x + edgev*w4.x + bb.x));
      pk.h[i+1] = f2bf(gelu_f(e.y + la*w0.y + rate*w1.y + sepv*w3.y + edgev*w4.y + bb.y));
      pk.h[i+2] = f2bf(gelu_f(e.z + la*w0.z + rate*w1.z + sepv*w3.z + edgev*w4.z + bb.z));
      pk.h[i+3] = f2bf(gelu_f(e.w + la*w0.w + rate*w1.w + sepv*w3.w + edgev*w4.w + bb.w));
    }
    int c = (rr >> 1) & 3;
    char* abase = (char*)Af + kc*2048 + rr*64;
    #pragma unroll
    for (int s = 0; s < 4; ++s)
      *(bf16x8*)(abase + ((s ^ c) << 4)) = pk.v[s];
  }
  __syncthreads();   // Af built AND Bs[0] landed

  f32x4 acc[2][4];
  #pragma unroll
  for (int i = 0; i < 2; ++i)
    #pragma unroll
    for (int j = 0; j < 4; ++j) acc[i][j] = (f32x4){0.f,0.f,0.f,0.f};

  int rgp = lane >> 4, li = lane & 15;
  for (int kc = 0; kc < 16; ++kc){
    int cur = kc & 1;
    if (kc < 15) stageB(cur ^ 1, kc + 1);
    bf16x8 a[2], bb[4];
    #pragma unroll
    for (int mt = 0; mt < 2; ++mt){
      int row = mt*16 + li;
      int slot = rgp ^ ((row >> 1) & 3);
      a[mt] = *(const bf16x8*)((const char*)Af + kc*2048 + row*64 + (slot << 4));
    }
    #pragma unroll
    for (int nt = 0; nt < 4; ++nt){
      int n = wid*64 + nt*16 + li;
      int slot = rgp ^ ((n >> 1) & 3);
      bb[nt] = *(const bf16x8*)((const char*)&Bs[cur][0] + n*64 + slot*16);
    }
    #pragma unroll
    for (int mt = 0; mt < 2; ++mt)
      #pragma unroll
      for (int nt = 0; nt < 4; ++nt)
        acc[mt][nt] = __builtin_amdgcn_mfma_f32_16x16x32_bf16(a[mt], bb[nt], acc[mt][nt], 0, 0, 0);
    __syncthreads();
  }

  // epilogue: h = gelu(y + s_vec[b] + gterm*wg + b1); partial dot with res_W2
  float svv[4], wgv[4], b1v[4], w2v[4];
  #pragma unroll
  for (int nt = 0; nt < 4; ++nt){
    int j = wid*64 + nt*16 + li;
    svv[nt] = s_vec[seg_b*DD + j];
    wgv[nt] = rW1[1024*DD + j];    // wg = res_W1 row 1024
    b1v[nt] = rb1[j];
    w2v[nt] = rW2[j];
  }
  #pragma unroll
  for (int mt = 0; mt < 2; ++mt){
    #pragma unroll
    for (int r = 0; r < 4; ++r){
      int row = mt*16 + rgp*4 + r;
      int p = seg_lo + row; if (p > seg_cnt-1) p = seg_cnt-1;
      int gr = alist[p];
      float gt = gterm_a[gr];
      float s = 0.f;
      #pragma unroll
      for (int nt = 0; nt < 4; ++nt){
        float y = acc[mt][nt][r] + svv[nt] + gt*wgv[nt] + b1v[nt];
        s += gelu_f(y) * w2v[nt];
      }
      s += __shfl_xor(s, 1, 64);
      s += __shfl_xor(s, 2, 64);
      s += __shfl_xor(s, 4, 64);
      s += __shfl_xor(s, 8, 64);
      if (li == 0) part[wid][row] = s;
    }
  }
  __syncthreads();
  if (tid < 32){
    int p = seg_lo + tid;
    if (p < seg_cnt){
      int gr = alist[p];
      float s = 0.f;
      #pragma unroll
      for (int w = 0; w < 8; ++w) s += part[w][tid];
      float resid = 0.35f * tanhf(s + rb2[0]) * rgate_a[gr];
      float g = gterm_a[gr];
      // active rows: speech==1, sil_commit==0
      out[gr] = fminf(fmaxf(g + resid, -1.2f), 1.2f);
    }
  }
}

extern "C" void kernel_launch(void* const* d_in, const int* in_sizes, int n_in,
                              void* d_out, int out_size, void* d_ws, size_t ws_size,
                              hipStream_t stream)
{
  const int*   content = (const int*)  d_in[0];
  const float* la      = (const float*)d_in[1];
  const int*   um      = (const int*)  d_in[2];
  const int*   smk     = (const int*)  d_in[3];
  const int*   zm      = (const int*)  d_in[4];
  const float* sep     = (const float*)d_in[5];
  const float* edge    = (const float*)d_in[6];
  const float* stab    = (const float*)d_in[7];
  const float* grate   = (const float*)d_in[8];
  const float* lre     = (const float*)d_in[9];
  const float* spk_e   = (const float*)d_in[10];
  const float* emb     = (const float*)d_in[11];
  const float* fW      = (const float*)d_in[12];
  const float* fb      = (const float*)d_in[13];
  const float* spk_W   = (const float*)d_in[14];
  const float* spk_b   = (const float*)d_in[15];
  const float* cW1     = (const float*)d_in[16];
  const float* cb1     = (const float*)d_in[17];
  const float* cW2     = (const float*)d_in[18];
  const float* cb2     = (const float*)d_in[19];
  const float* rW1     = (const float*)d_in[20];
  const float* rb1     = (const float*)d_in[21];
  const float* rW2     = (const float*)d_in[22];
  const float* rb2     = (const float*)d_in[23];

  char* w = (char*)d_ws;
  unsigned short* wsWqT = (unsigned short*)(w);                 // 524288 B
  size_t off = 524288;
  float* rate_seq = (float*)(w + off); off += MM*4;
  float* gterm_a  = (float*)(w + off); off += MM*4;
  float* rgate_a  = (float*)(w + off); off += MM*4;
  int*   active_list = (int*)(w + off); off += MM*4;
  float* s_vec    = (float*)(w + off); off += BB*DD*4;
  int*   acount   = (int*)(w + off); off += 256;

  fused_pre_kernel<<<72, 512, 0, stream>>>(spk_e, spk_W, spk_b, rW1, cW1, cb1,
      cW2, cb2, grate, la, um, smk, zm, stab, lre,
      wsWqT, s_vec, rate_seq, gterm_a, rgate_a, active_list, acount,
      (float*)d_out);
  gemm_kernel<<<MM/32, 512, 0, stream>>>(content, la, sep, edge, emb, fW, fb,
      rate_seq, wsWqT, s_vec, rW1, rb1, rW2, rb2,
      gterm_a, rgate_a, active_list, acount, (float*)d_out);
}

// Round 8
// 41.527 us; speedup vs baseline: 2.6218x; 2.6218x over previous
//
#include <hip/hip_runtime.h>
#include <hip/hip_bf16.h>

// ---- problem constants ----
#define BB 8
#define TT 4096
#define DD 512
#define MM (BB*TT)          // 32768 rows
#define DECAYF 0.95f
#define OMDECAYF (1.0f - 0.95f)

typedef __attribute__((ext_vector_type(8))) short bf16x8;
typedef __attribute__((ext_vector_type(4))) float f32x4;

__device__ __forceinline__ float gelu_f(float x){
  return 0.5f * x * (1.0f + erff(x * 0.70710678118654752f));
}

__device__ __forceinline__ unsigned short f2bf(float x){
  unsigned u = __float_as_uint(x);
  unsigned r = (u + 0x7FFFu + ((u >> 16) & 1u)) >> 16;
  return (unsigned short)r;
}

// ====== K1: blocks 0-63 prep1 (k-sliced) | 64-127 transpose | 128-135 scan ====
__global__ __launch_bounds__(512) void pre_kernel(
    const float* __restrict__ spk_embed, const float* __restrict__ spk_W,
    const float* __restrict__ spk_b, const float* __restrict__ rW1,
    const float* __restrict__ la_g, const int* __restrict__ um,
    const int* __restrict__ sm, const int* __restrict__ zm,
    const float* __restrict__ stab_g, const float* __restrict__ lre,
    float* __restrict__ spk_ctx, unsigned short* __restrict__ wqt,
    float* __restrict__ rate_seq, float* __restrict__ rgate_a,
    int* __restrict__ active_list, int* __restrict__ acount)
{
  __shared__ float se[DD];
  __shared__ float red[8][64];
  __shared__ float tile[64][65];
  __shared__ float wAg[8], wBg[8], wSg[8];
  __shared__ int wcnt[8];
  int blk = blockIdx.x, t = threadIdx.x;
  int lane = t & 63, wid = t >> 6;

  if (blk < 64){
    // ---- prep1: spk_ctx = tanh(spk_embed @ spk_W + spk_b), k-sliced ----
    int b = blk >> 3, d0 = (blk & 7) * 64;
    int dl = lane, ks = wid;
    se[t] = spk_embed[b*DD + t];
    __syncthreads();
    float a = 0.f;
    const float* wp = spk_W + (long)(ks*64)*DD + d0 + dl;
    #pragma unroll 8
    for (int k = 0; k < 64; ++k) a += se[ks*64 + k] * wp[(long)k*DD];
    red[ks][dl] = a;
    __syncthreads();
    if (t < 64){
      float s = spk_b[d0 + t];
      #pragma unroll
      for (int i = 0; i < 8; ++i) s += red[i][t];
      spk_ctx[b*DD + d0 + t] = tanhf(s);
    }
    return;
  }
  if (blk < 128){
    // ---- transpose Wq (k-major f32) -> WqT (n-major bf16) ----
    int tb = blk - 64;
    int nb = (tb & 7) * 64, kb = (tb >> 3) * 64;
    int tx = t & 63, ty = t >> 6;
    #pragma unroll
    for (int i = 0; i < 8; ++i){
      int k = ty + i*8;
      tile[k][tx] = rW1[(long)(kb + k)*DD + nb + tx];
    }
    __syncthreads();
    #pragma unroll
    for (int i = 0; i < 8; ++i){
      int nl = ty + i*8;
      wqt[(long)(nb + nl)*DD + kb + tx] = f2bf(tile[tx][nl]);
    }
    return;
  }

  // ---- scan: rate_seq + rgate + segmented compaction (batch b) ----
  int b = blk - 128;
  int base = b*TT + t*8;
  float4 la0 = *(const float4*)(la_g + base);
  float4 la1 = *(const float4*)(la_g + base + 4);
  int4 u0 = *(const int4*)(um + base), u1 = *(const int4*)(um + base + 4);
  int4 s0 = *(const int4*)(sm + base), s1 = *(const int4*)(sm + base + 4);
  int4 z0 = *(const int4*)(zm + base), z1 = *(const int4*)(zm + base + 4);
  float4 st0 = *(const float4*)(stab_g + base), st1 = *(const float4*)(stab_g + base + 4);
  float lav[8] = {la0.x,la0.y,la0.z,la0.w,la1.x,la1.y,la1.z,la1.w};
  int uv[8] = {u0.x,u0.y,u0.z,u0.w,u1.x,u1.y,u1.z,u1.w};
  int sv[8] = {s0.x,s0.y,s0.z,s0.w,s1.x,s1.y,s1.z,s1.w};
  int zv[8] = {z0.x,z0.y,z0.z,z0.w,z1.x,z1.y,z1.z,z1.w};
  float stv_[8] = {st0.x,st0.y,st0.z,st0.w,st1.x,st1.y,st1.z,st1.w};
  float spv[8], stv[8];

  float A = 1.f, Bv = 0.f, S = 0.f;
  #pragma unroll
  for (int i = 0; i < 8; ++i){
    float m = uv[i] > 0 ? 1.f : 0.f;
    float sealed = sv[i] > 0 ? 1.f : 0.f;
    float sil = (zv[i] > 0 ? 1.f : 0.f) * m;
    float speech = (m * sealed) * (1.f - sil);
    spv[i] = speech;
    stv[i] = fminf(fmaxf(stv_[i], 0.f), 1.f) * m;
    if (speech > 0.f){
      Bv = DECAYF*Bv + OMDECAYF*lav[i];
      A *= DECAYF;
      S += 1.f;
    }
  }
  #pragma unroll
  for (int d = 1; d < 64; d <<= 1){
    float Au = __shfl_up(A, d, 64);
    float Bu = __shfl_up(Bv, d, 64);
    float Su = __shfl_up(S, d, 64);
    if (lane >= d){ Bv = A*Bu + Bv; A = A*Au; S += Su; }
  }
  if (lane == 63){ wAg[wid] = A; wBg[wid] = Bv; wSg[wid] = S; }
  float Ale = __shfl_up(A, 1, 64), Ble = __shfl_up(Bv, 1, 64), Sle = __shfl_up(S, 1, 64);
  if (lane == 0){ Ale = 1.f; Ble = 0.f; Sle = 0.f; }
  __syncthreads();
  float Awp = 1.f, Bwp = 0.f, Swp = 0.f;
  for (int w = 0; w < wid; ++w){
    Bwp = wAg[w]*Bwp + wBg[w];
    Awp = wAg[w]*Awp;
    Swp += wSg[w];
  }
  float Bex = Ale*Bwp + Ble;
  float Aex = Ale*Awp;
  float Sex = Swp + Sle;

  float rate = Aex*lre[b] + Bex;
  float ps = Sex;
  float ro[8], rg[8];
  #pragma unroll
  for (int i = 0; i < 8; ++i){
    ro[i] = rate;
    float cold = fminf(ps * 0.5f, 1.f);                        // COLD_RUNS=2
    float shortg = fminf(fmaxf(expf(lav[i]) - 1.f, 0.f), 1.f); // MIN_DUR=2
    rg[i] = cold * shortg * stv[i] * spv[i];
    if (spv[i] > 0.f){
      rate = DECAYF*rate + OMDECAYF*lav[i];
      ps += 1.f;
    }
  }
  *(float4*)(rate_seq + base)     = make_float4(ro[0],ro[1],ro[2],ro[3]);
  *(float4*)(rate_seq + base + 4) = make_float4(ro[4],ro[5],ro[6],ro[7]);
  *(float4*)(rgate_a + base)      = make_float4(rg[0],rg[1],rg[2],rg[3]);
  *(float4*)(rgate_a + base + 4)  = make_float4(rg[4],rg[5],rg[6],rg[7]);

  int nact = 0;
  #pragma unroll
  for (int i = 0; i < 8; ++i) nact += (rg[i] != 0.f) ? 1 : 0;
  int inc = nact;
  #pragma unroll
  for (int d = 1; d < 64; d <<= 1){
    int u = __shfl_up(inc, d, 64);
    if (lane >= d) inc += u;
  }
  int myex = inc - nact;
  if (lane == 63) wcnt[wid] = inc;
  __syncthreads();
  int wbase = 0;
  for (int w = 0; w < wid; ++w) wbase += wcnt[w];
  int pos = wbase + myex;
  int* alist = active_list + b*TT;
  #pragma unroll
  for (int i = 0; i < 8; ++i){
    if (rg[i] != 0.f) alist[pos++] = base + i;
  }
  if (t == 0){
    int total = 0;
    #pragma unroll
    for (int w = 0; w < 8; ++w) total += wcnt[w];
    acount[b] = total;
  }
}

// ====== K2: s_vec = spk_ctx@Ws ; coarse hidden partial dot (k-sliced) =========
__global__ __launch_bounds__(512) void prep2_kernel(
    const float* __restrict__ spk_ctx, const float* __restrict__ rW1,
    const float* __restrict__ cW1, const float* __restrict__ cb1,
    const float* __restrict__ cW2, const float* __restrict__ grate,
    float* __restrict__ s_vec, float* __restrict__ coarse_part)
{
  __shared__ float sc[DD];
  __shared__ float red1[8][64];
  __shared__ float red2[8][64];
  int blk = blockIdx.x;
  int b = blk >> 3, d0 = (blk & 7) * 64;
  int t = threadIdx.x, dl = t & 63, ks = t >> 6;
  sc[t] = spk_ctx[b*DD + t];
  __syncthreads();
  float a1 = 0.f, a2 = 0.f;
  const float* wsp = rW1 + (long)(DD + ks*64)*DD + d0 + dl;   // Ws = res_W1[D:2D]
  const float* wcp = cW1 + (long)(ks*64)*DD + d0 + dl;
  #pragma unroll 4
  for (int k = 0; k < 64; ++k){
    float s = sc[ks*64 + k];
    a1 += s * wsp[(long)k*DD];
    a2 += s * wcp[(long)k*DD];
  }
  red1[ks][dl] = a1; red2[ks][dl] = a2;
  __syncthreads();
  if (t < 64){
    int d = d0 + t;
    float s1 = 0.f;
    float s2 = cb1[d] + grate[b] * cW1[(long)DD*DD + d];   // row 512 = grc coeff
    #pragma unroll
    for (int i = 0; i < 8; ++i){ s1 += red1[i][t]; s2 += red2[i][t]; }
    s_vec[b*DD + d] = s1;
    float hv = gelu_f(s2) * cW2[d];
    #pragma unroll
    for (int sh = 1; sh < 64; sh <<= 1) hv += __shfl_xor(hv, sh, 64);
    if (t == 0) coarse_part[blk] = hv;
  }
}

// ====== K3: blocks 0-63 baseline-out (rgate==0 rows); blocks 64+ gemm tiles ===
// gemm: BM=32, BN=512, BK=32, 8 waves; 3-buffer B staging, counted vmcnt(4)
__global__ __launch_bounds__(512) void main_kernel(
    const int* __restrict__ content, const float* __restrict__ la_g,
    const float* __restrict__ sep, const float* __restrict__ edge,
    const float* __restrict__ emb, const float* __restrict__ fW,
    const float* __restrict__ fb, const float* __restrict__ rate_seq,
    const unsigned short* __restrict__ wqt,
    const float* __restrict__ s_vec, const float* __restrict__ rW1,
    const float* __restrict__ rb1, const float* __restrict__ rW2,
    const float* __restrict__ rb2, const float* __restrict__ grate,
    const float* __restrict__ coarse_part, const float* __restrict__ cb2,
    const int* __restrict__ um, const int* __restrict__ sm,
    const int* __restrict__ zm,
    const float* __restrict__ rgate_a, const int* __restrict__ active_list,
    const int* __restrict__ acount, float* __restrict__ out)
{
  __shared__ unsigned short Af[16*32*32];    // [kc][row][32k] = 32 KB
  __shared__ unsigned short Bs[3][512*32];   // 96 KB, 3-deep pipeline
  __shared__ float part[8][32];
  __shared__ int seg_sh[3];
  int blk = blockIdx.x, tid = threadIdx.x, wid = tid >> 6, lane = tid & 63;

  if (blk < 64){
    // ---- baseline: write rows with rgate==0 (gemm writes the rest) ----
    int gr = blk*512 + tid;
    float rgv = rgate_a[gr];
    if (rgv == 0.f){
      int b = gr >> 12;
      float csum = cb2[0];
      #pragma unroll
      for (int c = 0; c < 8; ++c) csum += coarse_part[b*8 + c];
      float cs = 0.2f * tanhf(csum);
      float m = um[gr] > 0 ? 1.f : 0.f;
      float sealed = sm[gr] > 0 ? 1.f : 0.f;
      float sil = (zm[gr] > 0 ? 1.f : 0.f) * m;
      float commit = m * sealed;
      float speech = commit * (1.f - sil);
      float silc = commit * sil;
      float g = (grate[b] - rate_seq[gr] + cs) * commit;
      out[gr] = fminf(fmaxf(g, -1.2f), 1.2f) * speech
              + fminf(fmaxf(g, -0.35f), 0.35f) * silc;
    }
    return;
  }

  // ---- gemm tile ----
  if (tid == 0){
    int p = blk - 64, cum = 0, sb = -1, slo = 0, scnt = 0;
    #pragma unroll
    for (int b = 0; b < BB; ++b){
      int c = acount[b];
      int nb = (c + 31) >> 5;
      if (sb < 0 && p < cum + nb){ sb = b; slo = (p - cum) * 32; scnt = c; }
      cum += nb;
    }
    seg_sh[0] = sb; seg_sh[1] = slo; seg_sh[2] = scnt;
  }
  __syncthreads();
  int seg_b = seg_sh[0], seg_lo = seg_sh[1], seg_cnt = seg_sh[2];
  if (seg_b < 0) return;
  const int* alist = active_list + seg_b*TT;
  const char* wbase = (const char*)wqt;

  float csum = cb2[0];
  #pragma unroll
  for (int c = 0; c < 8; ++c) csum += coarse_part[seg_b*8 + c];
  float cs = 0.2f * tanhf(csum);
  float grc = grate[seg_b];

  auto stageB = [&](unsigned short* dstbuf, int kc){
    int k0b = kc * 64;  // byte offset into each 1024B (512-elem bf16) row
    #pragma unroll
    for (int i = 0; i < 4; ++i){
      int j = wid*4 + i;                      // 32 wave-issues for 512 n-rows
      int n = j*16 + (lane >> 2);
      int slot = (lane & 3) ^ ((n >> 1) & 3);
      const char* src = wbase + (long)n*1024 + k0b + slot*16;
      char* dst = (char*)dstbuf + j*1024 + (lane << 4);
      __builtin_amdgcn_global_load_lds(
          (const __attribute__((address_space(1))) void*)src,
          (__attribute__((address_space(3))) void*)dst, 16, 0, 0);
    }
  };

  // prologue: 2 buffers in flight; their latency hides under the A-build
  stageB(&Bs[0][0], 0);
  stageB(&Bs[1][0], 1);

  // ---- build A tile: thread -> row rr = tid>>4, k-chunk kc = tid&15 ----
  {
    int rr = tid >> 4, kc = tid & 15;
    int p = seg_lo + rr; if (p > seg_cnt-1) p = seg_cnt-1;
    int gr = alist[p];
    float la = la_g[gr], rate = rate_seq[gr];
    float sepv = sep[gr], edgev = edge[gr];
    int k0 = kc * 32;
    const float* er = emb + (long)content[gr]*DD + k0;
    union { bf16x8 v[4]; unsigned short h[32]; } pk;
    #pragma unroll
    for (int i = 0; i < 32; i += 4){
      float4 e  = *(const float4*)(er + i);
      float4 w0 = *(const float4*)(fW + 0*DD + k0 + i);
      float4 w1 = *(const float4*)(fW + 1*DD + k0 + i);
      float4 w3 = *(const float4*)(fW + 3*DD + k0 + i);
      float4 w4 = *(const float4*)(fW + 4*DD + k0 + i);
      float4 bb = *(const float4*)(fb + k0 + i);
      pk.h[i+0] = f2bf(gelu_f(e.x + la*w0.x + rate*w1.x + sepv*w3.x + edgev*w4.x + bb.x));
      pk.h[i+1] = f2bf(gelu_f(e.y + la*w0.y + rate*w1.y + sepv*w3.y + edgev*w4.y + bb.y));
      pk.h[i+2] = f2bf(gelu_f(e.z + la*w0.z + rate*w1.z + sepv*w3.z + edgev*w4.z + bb.z));
      pk.h[i+3] = f2bf(gelu_f(e.w + la*w0.w + rate*w1.w + sepv*w3.w + edgev*w4.w + bb.w));
    }
    int c = (rr >> 1) & 3;
    char* abase = (char*)Af + kc*2048 + rr*64;
    #pragma unroll
    for (int s = 0; s < 4; ++s)
      *(bf16x8*)(abase + ((s ^ c) << 4)) = pk.v[s];
  }
  __syncthreads();   // Af built; Bs[0],Bs[1] landed (full drain, once)

  f32x4 acc[2][4];
  #pragma unroll
  for (int i = 0; i < 2; ++i)
    #pragma unroll
    for (int j = 0; j < 4; ++j) acc[i][j] = (f32x4){0.f,0.f,0.f,0.f};

  int rgp = lane >> 4, li = lane & 15;
  #pragma unroll
  for (int kc = 0; kc < 16; ++kc){
    if (kc > 0){
      // wait only for cur's 4 loads (issued 2 iters ago); keep next's in flight
      if (kc < 15) asm volatile("s_waitcnt vmcnt(4)" ::: "memory");
      else         asm volatile("s_waitcnt vmcnt(0)" ::: "memory");
      __builtin_amdgcn_s_barrier();
      asm volatile("" ::: "memory");
    }
    if (kc + 2 < 16) stageB(&Bs[(kc+2)%3][0], kc+2);
    const char* bsb = (const char*)&Bs[kc%3][0];
    bf16x8 a[2], bb[4];
    #pragma unroll
    for (int mt = 0; mt < 2; ++mt){
      int row = mt*16 + li;
      int slot = rgp ^ ((row >> 1) & 3);
      a[mt] = *(const bf16x8*)((const char*)Af + kc*2048 + row*64 + (slot << 4));
    }
    #pragma unroll
    for (int nt = 0; nt < 4; ++nt){
      int n = wid*64 + nt*16 + li;
      int slot = rgp ^ ((n >> 1) & 3);
      bb[nt] = *(const bf16x8*)(bsb + n*64 + slot*16);
    }
    #pragma unroll
    for (int mt = 0; mt < 2; ++mt)
      #pragma unroll
      for (int nt = 0; nt < 4; ++nt)
        acc[mt][nt] = __builtin_amdgcn_mfma_f32_16x16x32_bf16(a[mt], bb[nt], acc[mt][nt], 0, 0, 0);
  }

  // epilogue: h = gelu(y + s_vec[b] + gterm*wg + b1); partial dot with res_W2
  float svv[4], wgv[4], b1v[4], w2v[4];
  #pragma unroll
  for (int nt = 0; nt < 4; ++nt){
    int j = wid*64 + nt*16 + li;
    svv[nt] = s_vec[seg_b*DD + j];
    wgv[nt] = rW1[1024*DD + j];    // wg = res_W1 row 1024
    b1v[nt] = rb1[j];
    w2v[nt] = rW2[j];
  }
  #pragma unroll
  for (int mt = 0; mt < 2; ++mt){
    #pragma unroll
    for (int r = 0; r < 4; ++r){
      int row = mt*16 + rgp*4 + r;
      int p = seg_lo + row; if (p > seg_cnt-1) p = seg_cnt-1;
      int gr = alist[p];
      float gt = grc - rate_seq[gr] + cs;    // active rows: commit==1
      float s = 0.f;
      #pragma unroll
      for (int nt = 0; nt < 4; ++nt){
        float y = acc[mt][nt][r] + svv[nt] + gt*wgv[nt] + b1v[nt];
        s += gelu_f(y) * w2v[nt];
      }
      s += __shfl_xor(s, 1, 64);
      s += __shfl_xor(s, 2, 64);
      s += __shfl_xor(s, 4, 64);
      s += __shfl_xor(s, 8, 64);
      if (li == 0) part[wid][row] = s;
    }
  }
  __syncthreads();
  if (tid < 32){
    int p = seg_lo + tid;
    if (p < seg_cnt){
      int gr = alist[p];
      float s = 0.f;
      #pragma unroll
      for (int w = 0; w < 8; ++w) s += part[w][tid];
      float resid = 0.35f * tanhf(s + rb2[0]) * rgate_a[gr];
      float g = grc - rate_seq[gr] + cs;
      // active rows: speech==1, sil_commit==0
      out[gr] = fminf(fmaxf(g + resid, -1.2f), 1.2f);
    }
  }
}

extern "C" void kernel_launch(void* const* d_in, const int* in_sizes, int n_in,
                              void* d_out, int out_size, void* d_ws, size_t ws_size,
                              hipStream_t stream)
{
  const int*   content = (const int*)  d_in[0];
  const float* la      = (const float*)d_in[1];
  const int*   um      = (const int*)  d_in[2];
  const int*   smk     = (const int*)  d_in[3];
  const int*   zm      = (const int*)  d_in[4];
  const float* sep     = (const float*)d_in[5];
  const float* edge    = (const float*)d_in[6];
  const float* stab    = (const float*)d_in[7];
  const float* grate   = (const float*)d_in[8];
  const float* lre     = (const float*)d_in[9];
  const float* spk_e   = (const float*)d_in[10];
  const float* emb     = (const float*)d_in[11];
  const float* fW      = (const float*)d_in[12];
  const float* fb      = (const float*)d_in[13];
  const float* spk_W   = (const float*)d_in[14];
  const float* spk_b   = (const float*)d_in[15];
  const float* cW1     = (const float*)d_in[16];
  const float* cb1     = (const float*)d_in[17];
  const float* cW2     = (const float*)d_in[18];
  const float* cb2     = (const float*)d_in[19];
  const float* rW1     = (const float*)d_in[20];
  const float* rb1     = (const float*)d_in[21];
  const float* rW2     = (const float*)d_in[22];
  const float* rb2     = (const float*)d_in[23];

  char* w = (char*)d_ws;
  unsigned short* wsWqT = (unsigned short*)(w);                 // 524288 B
  size_t off = 524288;
  float* rate_seq = (float*)(w + off); off += MM*4;
  float* rgate_a  = (float*)(w + off); off += MM*4;
  int*   active_list = (int*)(w + off); off += MM*4;
  float* s_vec    = (float*)(w + off); off += BB*DD*4;
  float* spk_ctx  = (float*)(w + off); off += BB*DD*4;
  float* coarse_part = (float*)(w + off); off += 64*4;
  int*   acount   = (int*)(w + off); off += 256;

  pre_kernel<<<136, 512, 0, stream>>>(spk_e, spk_W, spk_b, rW1,
      la, um, smk, zm, stab, lre,
      spk_ctx, wsWqT, rate_seq, rgate_a, active_list, acount);
  prep2_kernel<<<64, 512, 0, stream>>>(spk_ctx, rW1, cW1, cb1, cW2, grate,
                                       s_vec, coarse_part);
  main_kernel<<<64 + MM/32, 512, 0, stream>>>(content, la, sep, edge, emb, fW, fb,
      rate_seq, wsWqT, s_vec, rW1, rb1, rW2, rb2, grate, coarse_part, cb2,
      um, smk, zm, rgate_a, active_list, acount, (float*)d_out);
}